// Round 4
// baseline (196.037 us; speedup 1.0000x reference)
//
#include <hip/hip_runtime.h>
#include <stdint.h>

typedef __bf16 bf16_t;
typedef __bf16 bf16x8 __attribute__((ext_vector_type(8)));
typedef float f32x4 __attribute__((ext_vector_type(4)));
typedef float f32x16 __attribute__((ext_vector_type(16)));
typedef unsigned int u32x2 __attribute__((ext_vector_type(2)));

#define DEV __device__ __forceinline__

DEV void gload_lds16(const void* g, void* lds) {
  __builtin_amdgcn_global_load_lds(
      (const __attribute__((address_space(1))) uint32_t*)g,
      (__attribute__((address_space(3))) uint32_t*)lds, 16, 0, 0);
}

DEV float fexp2(float x) {
#if __has_builtin(__builtin_amdgcn_exp2f)
  return __builtin_amdgcn_exp2f(x);
#else
  return exp2f(x);
#endif
}

DEV uint32_t pk_bf16(float a, float b) {
  uint32_t lo = (uint32_t)__builtin_bit_cast(uint16_t, (bf16_t)a);
  uint32_t hi = (uint32_t)__builtin_bit_cast(uint16_t, (bf16_t)b);
  return lo | (hi << 16);
}

// ---------------------------------------------------------------- K0: hs -> bf16
__global__ __launch_bounds__(256) void cvt_hs(const float* __restrict__ x,
                                              bf16_t* __restrict__ y) {
  int i = blockIdx.x * 256 + threadIdx.x;
  float4 v = ((const float4*)x)[i];
  ((uint2*)y)[i] = make_uint2(pk_bf16(v.x, v.y), pk_bf16(v.z, v.w));
}

// ------------------------------------------- K1: W[k][n] (x3) -> WT[n][k] bf16
__global__ __launch_bounds__(256) void cvt_w(const float* __restrict__ Wq,
                                             const float* __restrict__ Wk,
                                             const float* __restrict__ Wv,
                                             bf16_t* __restrict__ WT) {
  __shared__ float T[32][36];
  const int bx = blockIdx.x;   // n tile 0..71 (over 2304)
  const int by = blockIdx.y;   // k tile 0..23 (over 768)
  const int p = bx / 24;
  const float* W = (p == 0) ? Wq : ((p == 1) ? Wk : Wv);
  const int n0 = bx * 32, nn0 = n0 - p * 768, k0 = by * 32;
  const int t = threadIdx.x;
  {
    int r = t >> 3, c4 = (t & 7) * 4;
    float4 v = *(const float4*)&W[(size_t)(k0 + r) * 768 + nn0 + c4];
    T[r][c4 + 0] = v.x; T[r][c4 + 1] = v.y; T[r][c4 + 2] = v.z; T[r][c4 + 3] = v.w;
  }
  __syncthreads();
  {
    int nr = t >> 3, kc = (t & 7) * 4;
    uint32_t lo = pk_bf16(T[kc + 0][nr], T[kc + 1][nr]);
    uint32_t hi = pk_bf16(T[kc + 2][nr], T[kc + 3][nr]);
    *(uint2*)&WT[(size_t)(n0 + nr) * 768 + k0 + kc] = make_uint2(lo, hi);
  }
}

// ------------------------------------------------- K2: C[4096,2304] = A @ W (+b)
// K-projection output is pre-scaled by log2(e)/8 (softmax scale folded in).
// v2: double-buffered LDS pipeline (round-3 win; gemm 43 -> <~30 us).
__global__ __launch_bounds__(256) void gemm_qkv(
    const bf16_t* __restrict__ A, const bf16_t* __restrict__ Wt,
    const float* __restrict__ bq, const float* __restrict__ bk,
    const float* __restrict__ bv, bf16_t* __restrict__ Qo,
    bf16_t* __restrict__ Ko, bf16_t* __restrict__ VTo) {
  __shared__ __align__(16) char smem[65536];  // 2 x (As 16K + Bs 16K); Cs union
  bf16_t* Cs = (bf16_t*)smem;  // 128x136 epilogue scratch
  const int bx = blockIdx.x;  // 0..17 (n)
  const int by = blockIdx.y;  // 0..31 (m)
  const int m0 = by * 128, n0 = bx * 128;
  const int tid = threadIdx.x, w = tid >> 6, lane = tid & 63;
  const int mw = (w & 1) * 64, nw = (w >> 1) * 64;
  const int quad = lane >> 4, col = lane & 15;

  f32x4 acc[4][4];
  for (int i = 0; i < 4; i++)
    for (int j = 0; j < 4; j++) acc[i][j] = (f32x4){0.f, 0.f, 0.f, 0.f};

  const int srow = w * 32 + (lane >> 3);
  const int scol = (lane & 7) * 8;
  const bf16_t* ag = A + (size_t)(m0 + srow) * 768 + scol;
  const bf16_t* bg = Wt + (size_t)(n0 + srow) * 768 + scol;

  auto stageg = [&](int kk, int bf) {
    const int k0 = kk * 64;
    bf16_t* dA = (bf16_t*)(smem + bf * 32768) + (w * 32) * 64;
    bf16_t* dB = (bf16_t*)(smem + bf * 32768 + 16384) + (w * 32) * 64;
#pragma unroll
    for (int i = 0; i < 4; i++) {
      gload_lds16(ag + (size_t)i * 8 * 768 + k0, dA + i * 8 * 64);
      gload_lds16(bg + (size_t)i * 8 * 768 + k0, dB + i * 8 * 64);
    }
  };

  stageg(0, 0);
  __syncthreads();  // one exposed drain at prologue only

  for (int kk = 0; kk < 12; ++kk) {
    const int bf = kk & 1;
    if (kk < 11) stageg(kk + 1, bf ^ 1);
    __builtin_amdgcn_sched_barrier(0);  // pin load issue ahead of compute
    const bf16_t* As = (const bf16_t*)(smem + bf * 32768);
    const bf16_t* Bs = (const bf16_t*)(smem + bf * 32768 + 16384);
#pragma unroll
    for (int ks = 0; ks < 2; ++ks) {
      bf16x8 af[4], bfr[4];
#pragma unroll
      for (int mt = 0; mt < 4; ++mt)
        af[mt] = *(const bf16x8*)&As[(mw + mt * 16 + col) * 64 + ks * 32 + quad * 8];
#pragma unroll
      for (int nt = 0; nt < 4; ++nt)
        bfr[nt] = *(const bf16x8*)&Bs[(nw + nt * 16 + col) * 64 + ks * 32 + quad * 8];
#pragma unroll
      for (int mt = 0; mt < 4; ++mt)
#pragma unroll
        for (int nt = 0; nt < 4; ++nt)
          acc[mt][nt] = __builtin_amdgcn_mfma_f32_16x16x32_bf16(
              af[mt], bfr[nt], acc[mt][nt], 0, 0, 0);
    }
    __syncthreads();  // publishes stage(kk+1); all reads of buf done
  }

  const int p = bx / 6;
  const float* bp = (p == 0) ? bq : ((p == 1) ? bk : bv);
  const float kscale = (p == 1) ? 0.18033688011112042f : 1.0f;  // log2(e)/sqrt(64)
  const int bb0 = m0 >> 11, s0 = m0 & 2047;
  if (p < 2) {
#pragma unroll
    for (int nt = 0; nt < 4; nt++) {
      int n = nw + nt * 16 + col;
      float bias = bp[n0 + n - p * 768];
#pragma unroll
      for (int mt = 0; mt < 4; mt++)
#pragma unroll
        for (int r = 0; r < 4; r++) {
          int m = mw + mt * 16 + quad * 4 + r;
          Cs[m * 136 + n] = (bf16_t)((acc[mt][nt][r] + bias) * kscale);
        }
    }
    __syncthreads();
    bf16_t* dst = (p == 0) ? Qo : Ko;
#pragma unroll
    for (int i = 0; i < 8; i++) {
      int idx = i * 256 + tid;
      int m = idx >> 4, c = idx & 15;
      bf16x8 v = *(const bf16x8*)&Cs[m * 136 + c * 8];
      int nn = n0 - p * 768 + c * 8;
      int hq = nn >> 6, hd = nn & 63;
      *(bf16x8*)&dst[(size_t)((bb0 * 12 + hq) * 2048 + s0 + m) * 64 + hd] = v;
    }
  } else {
#pragma unroll
    for (int nt = 0; nt < 4; nt++) {
      int n = nw + nt * 16 + col;
      float bias = bp[n0 + n - 1536];
#pragma unroll
      for (int mt = 0; mt < 4; mt++)
#pragma unroll
        for (int r = 0; r < 4; r++) {
          int m = mw + mt * 16 + quad * 4 + r;
          Cs[n * 136 + m] = (bf16_t)(acc[mt][nt][r] + bias);
        }
    }
    __syncthreads();
#pragma unroll
    for (int i = 0; i < 8; i++) {
      int idx = i * 256 + tid;
      int n = idx >> 4, c = idx & 15;
      bf16x8 v = *(const bf16x8*)&Cs[n * 136 + c * 8];
      int nn = n0 - 1536 + n;
      int hq = nn >> 6, hd = nn & 63;
      *(bf16x8*)&VTo[((size_t)(bb0 * 12 + hq) * 64 + hd) * 2048 + s0 + c * 8] = v;
    }
  }
}

// ---------------------------------------------------------------- K3: attention
// v8: occupancy push. Round-3 evidence: per-SIMD issue ~16% busy at exactly
// 3 blocks/CU (LDS-capped, grid-capped); latency-bound. Now KVBLK=32 (K+V
// buffer 8KB, 3-buf = 24KB LDS) and ksplit=4 -> grid 1536 = 6 blocks/CU =
// 24 waves/CU = 6 waves/SIMD. Per-iter work halves (8 MFMA, 16 exp2); same
// counted-vmcnt 2-deep prefetch. V stored d-pair-packed (row'=d>>1, 128B
// rows) so the row&7 XOR swizzle keeps reads ~conflict-free. Epilogue LDS
// transpose runs in 2 phases (24KB scratch < 4x8KB).
__global__ __launch_bounds__(256, 6) void attn(const bf16_t* __restrict__ Q,
                                               const bf16_t* __restrict__ K,
                                               const bf16_t* __restrict__ VT,
                                               float* __restrict__ Op,
                                               float* __restrict__ lp) {
  __shared__ __align__(16) char smem[24576];
  bf16_t* Kl = (bf16_t*)smem;             // [3][32key x 64d], 16B-chunk XOR swz
  bf16_t* Vl = (bf16_t*)(smem + 12288);   // [3][32row' x 64], d-pair-packed
  const int id = blockIdx.x;              // 0..1535
  const int rr0 = id >> 3;                // 0..191
  const int bh = (id & 7) * 3 + (rr0 >> 6);  // XCD id&7 owns 3 consecutive bh
  const int w5 = rr0 & 63;
  const int qt = w5 & 15, sp = w5 >> 4;   // q-tile 0..15, key-split 0..3
  const int tid = threadIdx.x, wv = tid >> 6, lane = tid & 63;
  const int lq = lane & 31, half = lane >> 5;
  const int q0 = qt * 128 + wv * 32;

  bf16x8 qf[4];  // B-frags of Q^T (per-lane query = lq), register resident
#pragma unroll
  for (int ks = 0; ks < 4; ++ks)
    qf[ks] = *(const bf16x8*)&Q[(size_t)(bh * 2048 + q0 + lq) * 64 + ks * 16 + half * 8];

  f32x16 oacc[2];  // O^T partial: col=q (lane), rows=d
  for (int i = 0; i < 16; i++) { oacc[0][i] = 0.f; oacc[1][i] = 0.f; }
  float l0 = 0.f, l1 = 0.f, l2 = 0.f, l3 = 0.f;  // partial denominators

  const bf16_t* gK = K + ((size_t)bh * 2048 + sp * 512) * 64;
  const bf16_t* gV = VT + (size_t)bh * 64 * 2048 + sp * 512;
  const int l8 = lane >> 3, l7 = lane & 7;

  // per-lane source offsets for the 2 staged 1KB chunks of this wave
  int iiA[2];
  size_t soff[2];
#pragma unroll
  for (int i = 0; i < 2; i++) {
    int ii = (wv & 1) * 2 + i;
    iiA[i] = ii;
    int rl = ii * 8 + l8;        // K: key row 0..31 | V: packed row' 0..31
    int cs = l7 ^ (rl & 7);      // logical chunk held at this lane's slot
    if (wv < 2) {
      soff[i] = (size_t)rl * 64 + cs * 8;                    // K[key][d-chunk]
    } else {
      int d = rl * 2 + (cs >> 2), kc = cs & 3;               // V[d][key-chunk]
      soff[i] = (size_t)d * 2048 + kc * 8;
    }
  }

  auto stage = [&](int kb, int buf) {
    if (wv < 2) {
#pragma unroll
      for (int i = 0; i < 2; i++)
        gload_lds16(gK + (size_t)kb * 2048 + soff[i], Kl + buf * 2048 + iiA[i] * 512);
    } else {
#pragma unroll
      for (int i = 0; i < 2; i++)
        gload_lds16(gV + soff[i] + kb * 32, Vl + buf * 2048 + iiA[i] * 512);
    }
  };

  stage(0, 0);
  stage(1, 1);
  asm volatile("s_waitcnt vmcnt(2)" ::: "memory");  // buf0 (+Q) done; buf1 flying
  __builtin_amdgcn_s_barrier();
  asm volatile("" ::: "memory");

  int bb = 0, rb = 2;
  for (int kb = 0; kb < 16; ++kb) {
    if (kb < 14) stage(kb + 2, rb);  // 2-deep prefetch, in flight across barriers

    // S^T[key][q] = K_blk @ Q^T   (K pre-scaled by log2e/8 at projection)
    f32x16 sacc;
    for (int i = 0; i < 16; i++) sacc[i] = 0.f;
    __builtin_amdgcn_s_setprio(1);
#pragma unroll
    for (int ks = 0; ks < 4; ++ks) {
      bf16x8 kf = *(const bf16x8*)&Kl[bb * 2048 + lq * 64 + (((2 * ks + half) ^ (lq & 7)) * 8)];
      sacc = __builtin_amdgcn_mfma_f32_32x32x16_bf16(kf, qf[ks], sacc, 0, 0, 0);
    }
    __builtin_amdgcn_s_setprio(0);

    // P = exp2(S) (fixed max), l in 4 partial chains
#pragma unroll
    for (int rr = 0; rr < 16; rr++) sacc[rr] = fexp2(sacc[rr]);
#pragma unroll
    for (int rr = 0; rr < 16; rr += 4) {
      l0 += sacc[rr + 0];
      l1 += sacc[rr + 1];
      l2 += sacc[rr + 2];
      l3 += sacc[rr + 3];
    }

    // pack quads: pkq[g] = keys 8g + 4*half + {0..3}, as 2x u32
    uint32_t pkq[4][2];
#pragma unroll
    for (int g = 0; g < 4; g++) {
      pkq[g][0] = pk_bf16(sacc[4 * g + 0], sacc[4 * g + 1]);
      pkq[g][1] = pk_bf16(sacc[4 * g + 2], sacc[4 * g + 3]);
    }

    // cross-half exchange -> B-operand frags via permlane32_swap
    bf16x8 pfrag[2];
#pragma unroll
    for (int e = 0; e < 2; e++) {
      union { uint32_t u[4]; bf16x8 v; } F;
#pragma unroll
      for (int wd = 0; wd < 2; wd++) {
#if __has_builtin(__builtin_amdgcn_permlane32_swap)
        u32x2 sw = __builtin_amdgcn_permlane32_swap(pkq[2 * e][wd],
                                                    pkq[2 * e + 1][wd],
                                                    false, false);
        F.u[wd] = sw.x;
        F.u[2 + wd] = sw.y;
#else
        uint32_t s = half ? pkq[2 * e][wd] : pkq[2 * e + 1][wd];
        uint32_t rx = __shfl_xor(s, 32);
        uint32_t ow = half ? pkq[2 * e + 1][wd] : pkq[2 * e][wd];
        F.u[wd] = half ? rx : ow;
        F.u[2 + wd] = half ? ow : rx;
#endif
      }
      pfrag[e] = F.v;
    }

    // O^T += V^T @ P^T  (A = V frags from LDS, B = pfrag)
    __builtin_amdgcn_s_setprio(1);
#pragma unroll
    for (int c = 0; c < 2; c++) {
#pragma unroll
      for (int dt = 0; dt < 2; dt++) {
        const int d = dt * 32 + lq;
        const int rp = d >> 1;
        const int cp = (d & 1) * 4 + 2 * c + half;
        bf16x8 vf = *(const bf16x8*)&Vl[bb * 2048 + rp * 64 + ((cp ^ (rp & 7)) * 8)];
        oacc[dt] = __builtin_amdgcn_mfma_f32_32x32x16_bf16(vf, pfrag[c], oacc[dt], 0, 0, 0);
      }
    }
    __builtin_amdgcn_s_setprio(0);

    // counted wait: keep newest stage batch (2 loads/wave) in flight
    if (kb < 14) {
      asm volatile("s_waitcnt vmcnt(2)" ::: "memory");
    } else if (kb == 14) {
      asm volatile("s_waitcnt vmcnt(0)" ::: "memory");
    }
    if (kb < 15) {
      __builtin_amdgcn_s_barrier();
      asm volatile("" ::: "memory");
    }
    bb = (bb == 2) ? 0 : bb + 1;
    rb = (rb == 2) ? 0 : rb + 1;
  }

  // epilogue: partial l + unnormalized partial O^T -> Op[q][d] rows.
  // 24KB scratch < 4 waves x 8KB -> two phases (waves 0-2, then wave 3).
  float l_own = (l0 + l1) + (l2 + l3);
  float l_tot = l_own + __shfl_xor(l_own, 32);
  if (half == 0) lp[((size_t)sp * 24 + bh) * 2048 + q0 + lq] = l_tot;
  float* ob = Op + (((size_t)sp * 24 + bh) * 2048 + q0) * 64;
  __syncthreads();  // all K/V reads done; smem becomes f32 scratch
#pragma unroll
  for (int ph = 0; ph < 2; ++ph) {
    if (ph == 0 ? (wv < 3) : (wv == 3)) {
      float* Of = (float*)smem + (ph == 0 ? wv : 0) * 2048;
#pragma unroll
      for (int dt = 0; dt < 2; dt++)
#pragma unroll
        for (int rr = 0; rr < 16; rr++) {
          int d = dt * 32 + (rr & 3) + 8 * (rr >> 2) + 4 * half;
          int g = d >> 2, wd = d & 3;
          Of[lq * 64 + ((g ^ (lq & 15)) * 4) + wd] = oacc[dt][rr];
        }
#pragma unroll
      for (int i = 0; i < 8; i++) {
        int idx = i * 64 + lane;
        int qq = idx >> 4, c = idx & 15;
        f32x4 v = *(f32x4*)&Of[qq * 64 + ((c ^ (qq & 15)) * 4)];
        *(f32x4*)&ob[(size_t)qq * 64 + c * 4] = v;
      }
    }
    __syncthreads();
  }
}

// ------------------------------------------------- K4: combine split-K partials
// out[b][q][h*64+d] = sum_p Op[p] / sum_p l[p], with head-merge transpose.
__global__ __launch_bounds__(256) void combine(const float* __restrict__ Op,
                                               const float* __restrict__ lp,
                                               float* __restrict__ out) {
  int g = blockIdx.x * 256 + threadIdx.x;  // over 24*2048*16 = 786432
  int bh = g >> 15;
  int rem = g & 32767;
  int q = rem >> 4, c = rem & 15;
  const size_t plane = (size_t)24 * 2048 * 64;
  size_t o0 = ((size_t)bh * 2048 + q) * 64 + c * 4;
  f32x4 s = (f32x4){0.f, 0.f, 0.f, 0.f};
  float l = 0.f;
#pragma unroll
  for (int p = 0; p < 4; p++) {
    f32x4 a = *(const f32x4*)&Op[p * plane + o0];
    l += lp[((size_t)p * 24 + bh) * 2048 + q];
#pragma unroll
    for (int j = 0; j < 4; j++) s[j] += a[j];
  }
  float inv = 1.0f / l;
  int b = bh / 12, head = bh % 12;
  f32x4 r;
#pragma unroll
  for (int j = 0; j < 4; j++) r[j] = s[j] * inv;
  *(f32x4*)&out[((size_t)b * 2048 + q) * 768 + head * 64 + c * 4] = r;
}

// -------------------------------------------------------------------- launcher
extern "C" void kernel_launch(void* const* d_in, const int* in_sizes, int n_in,
                              void* d_out, int out_size, void* d_ws, size_t ws_size,
                              hipStream_t stream) {
  const float* hs = (const float*)d_in[0];
  const float* Wq = (const float*)d_in[1];
  const float* bq = (const float*)d_in[2];
  const float* Wk = (const float*)d_in[3];
  const float* bk = (const float*)d_in[4];
  const float* Wv = (const float*)d_in[5];
  const float* bv = (const float*)d_in[6];
  float* out = (float*)d_out;

  char* w = (char*)d_ws;
  bf16_t* hsb = (bf16_t*)w; w += (size_t)4096 * 768 * 2;
  bf16_t* wtb = (bf16_t*)w; w += (size_t)2304 * 768 * 2;
  bf16_t* Qb  = (bf16_t*)w; w += (size_t)24 * 2048 * 64 * 2;
  bf16_t* Kb  = (bf16_t*)w; w += (size_t)24 * 2048 * 64 * 2;
  bf16_t* VTb = (bf16_t*)w; w += (size_t)24 * 2048 * 64 * 2;
  float* Opw  = (float*)w;  w += (size_t)4 * 24 * 2048 * 64 * 4;  // 50.3 MB
  float* lpw  = (float*)w;                                        // 0.79 MB

  hipLaunchKernelGGL(cvt_hs, dim3(3072), dim3(256), 0, stream, hs, hsb);
  hipLaunchKernelGGL(cvt_w, dim3(72, 24), dim3(256), 0, stream, Wq, Wk, Wv, wtb);
  hipLaunchKernelGGL(gemm_qkv, dim3(18, 32), dim3(256), 0, stream, hsb, wtb, bq,
                     bk, bv, Qb, Kb, VTb);
  hipLaunchKernelGGL(attn, dim3(1536), dim3(256), 0, stream, Qb, Kb, VTb, Opw, lpw);
  hipLaunchKernelGGL(combine, dim3(3072), dim3(256), 0, stream, Opw, lpw, out);
}